// Round 6
// baseline (347.564 us; speedup 1.0000x reference)
//
#include <hip/hip_runtime.h>

#define T_TOK 2048
#define DIM   512
#define MOE   256
#define NE    64
#define NG    8
#define TOPKG 4
#define TOPK  8
#define CAP   1024
#define MOE_SCALE 2.5f

typedef float f32x4 __attribute__((ext_vector_type(4)));
typedef short s16x8 __attribute__((ext_vector_type(8)));

__device__ __forceinline__ unsigned short f2bf(float f) {
    unsigned u = __builtin_bit_cast(unsigned, f);
    unsigned r = (u + 0x7fffu + ((u >> 16) & 1u)) >> 16;
    return (unsigned short)r;
}

// ---------------- Fused gating + x->bf16 conversion, one wave per token -------
__global__ __launch_bounds__(256) void gate_fused_k(const float* __restrict__ x,
                                                    const float* __restrict__ gw,
                                                    const float* __restrict__ gb,
                                                    int* __restrict__ counts,
                                                    int* __restrict__ etok,
                                                    float* __restrict__ wt_of,
                                                    short* __restrict__ xb)
{
    int t = blockIdx.x * 4 + (threadIdx.x >> 6);
    int lane = threadIdx.x & 63;

    // lane e: dot(x[t], gw[e]) over 512 (4 partial accs to break the chain)
    const float4* xr = (const float4*)(x + (size_t)t * DIM);
    const float4* wr = (const float4*)(gw + (size_t)lane * DIM);
    float a0 = 0.f, a1 = 0.f, a2 = 0.f, a3 = 0.f;
#pragma unroll 8
    for (int i = 0; i < DIM / 4; i += 4) {
        float4 x0 = xr[i],     w0 = wr[i];
        float4 x1 = xr[i + 1], w1 = wr[i + 1];
        float4 x2 = xr[i + 2], w2 = wr[i + 2];
        float4 x3 = xr[i + 3], w3 = wr[i + 3];
        a0 += x0.x * w0.x + x0.y * w0.y + x0.z * w0.z + x0.w * w0.w;
        a1 += x1.x * w1.x + x1.y * w1.y + x1.z * w1.z + x1.w * w1.w;
        a2 += x2.x * w2.x + x2.y * w2.y + x2.z * w2.z + x2.w * w2.w;
        a3 += x3.x * w3.x + x3.y * w3.y + x3.z * w3.z + x3.w * w3.w;
    }
    float acc = (a0 + a1) + (a2 + a3);
    float sc = 1.f / (1.f + __expf(-acc));   // pre-bias score
    float s  = sc + gb[lane];                 // biased score

    // x -> bf16 (lane writes its 16-B chunk, coalesced)
    {
        const float4* src = (const float4*)(x + (size_t)t * DIM + lane * 8);
        float4 f0 = src[0], f1 = src[1];
        short o[8];
        o[0] = (short)f2bf(f0.x); o[1] = (short)f2bf(f0.y);
        o[2] = (short)f2bf(f0.z); o[3] = (short)f2bf(f0.w);
        o[4] = (short)f2bf(f1.x); o[5] = (short)f2bf(f1.y);
        o[6] = (short)f2bf(f1.z); o[7] = (short)f2bf(f1.w);
        *(s16x8*)(xb + (size_t)t * DIM + lane * 8) = *(const s16x8*)o;
    }

    // group top-2 sum within each 8-lane group
    float m1 = s, m2 = -1e30f;
#pragma unroll
    for (int d = 1; d < 8; d <<= 1) {
        float o1 = __shfl_xor(m1, d);
        float o2 = __shfl_xor(m2, d);
        float n1 = fmaxf(m1, o1);
        float n2 = fmaxf(fminf(m1, o1), fmaxf(m2, o2));
        m1 = n1; m2 = n2;
    }
    float gv = m1 + m2;

    // top-4 groups (tie -> lowest group index)
    bool gkeep = false;
#pragma unroll
    for (int it = 0; it < TOPKG; ++it) {
        float m = gv;
#pragma unroll
        for (int d = 1; d < 64; d <<= 1) m = fmaxf(m, __shfl_xor(m, d));
        unsigned long long mask = __ballot(gv == m);
        int ldr = __ffsll(mask) - 1;
        if ((lane >> 3) == (ldr >> 3)) { gkeep = true; gv = -2e30f; }
    }
    float sv = gkeep ? s : -1e30f;

    // top-8 experts (tie -> lowest index)
    float wsum = 0.f;
    int my_e = 0; float my_w = 0.f;
#pragma unroll
    for (int k = 0; k < TOPK; ++k) {
        float m = sv;
#pragma unroll
        for (int d = 1; d < 64; d <<= 1) m = fmaxf(m, __shfl_xor(m, d));
        unsigned long long mask = __ballot(sv == m);
        int l = __ffsll(mask) - 1;
        float wk = __shfl(sc, l);
        wsum += wk;
        if (lane == k) { my_e = l; my_w = wk; }
        if (lane == l) sv = -2e30f;
    }
    float scale = MOE_SCALE / wsum;
    if (lane < TOPK) {
        int p = atomicAdd(&counts[my_e], 1);
        int rid = t * TOPK + lane;           // global slot id
        bool ok = (p < CAP);
        if (ok) etok[my_e * CAP + p] = rid;
        wt_of[rid] = ok ? my_w * scale : 0.f;
    }
}

// ---------------- K1: h = silu(X@W1)*(X@W3) --------------------------------
// Block = (expert, 64-col group of MOE). W1/W3 slice cooperatively staged into
// LDS bf16 in MFMA-B-frag layout (coalesced fp32 reads, weights read ONCE).
// 8 waves then stream token tiles (M=32) with ds_read_b128 B-frags.
__global__ __launch_bounds__(512) void gemm1_k(const short* __restrict__ xb,
                                               const float* __restrict__ w1,
                                               const float* __restrict__ w3,
                                               const int* __restrict__ counts,
                                               const int* __restrict__ etok,
                                               short* __restrict__ hbuf)
{
    __shared__ short Bl[2][4][16][64][8];   // mat, s, kt, flane, j  = 128 KB

    int e  = blockIdx.x >> 2, cg = blockIdx.x & 3;
    int n0 = cg * 64;
    int tid = threadIdx.x;
    int w = tid >> 6, lane = tid & 63;
    int q = lane >> 4, m16 = lane & 15;

    // ---- stage: coalesced fp32 rows -> bf16 frag-major LDS ----
    {
        const float* W0 = w1 + (size_t)e * DIM * MOE + n0 + lane;
        const float* W1p = w3 + (size_t)e * DIM * MOE + n0 + lane;
        int s = lane >> 4, c15 = lane & 15;
#pragma unroll 4
        for (int kk = 0; kk < 64; ++kk) {
            int k = w * 64 + kk;
            int kt = k >> 5, qq = (k >> 3) & 3, j = k & 7;
            Bl[0][s][kt][qq * 16 + c15][j] = (short)f2bf(W0[(size_t)k * MOE]);
            Bl[1][s][kt][qq * 16 + c15][j] = (short)f2bf(W1p[(size_t)k * MOE]);
        }
    }
    __syncthreads();

    int n_e = min(counts[e], CAP);
    int ntiles = (n_e + 31) >> 5;
    const int* el = etok + e * CAP;

    for (int tile = w; tile < ntiles; tile += 8) {
        int r0 = tile * 32;
        int row0 = r0 + m16, row1 = r0 + 16 + m16;
        int rid0 = el[row0 < n_e ? row0 : n_e - 1];
        int rid1 = el[row1 < n_e ? row1 : n_e - 1];
        const short* A0 = xb + (size_t)(rid0 >> 3) * DIM + q * 8;
        const short* A1 = xb + (size_t)(rid1 >> 3) * DIM + q * 8;

        f32x4 g0[4], g1[4], u0[4], u1[4];
#pragma unroll
        for (int s = 0; s < 4; ++s) {
            g0[s] = (f32x4)0.f; g1[s] = (f32x4)0.f;
            u0[s] = (f32x4)0.f; u1[s] = (f32x4)0.f;
        }
#pragma unroll
        for (int kt = 0; kt < 16; ++kt) {
            s16x8 a0 = *(const s16x8*)(A0 + kt * 32);
            s16x8 a1 = *(const s16x8*)(A1 + kt * 32);
#pragma unroll
            for (int s = 0; s < 4; ++s) {
                s16x8 b1 = *(const s16x8*)&Bl[0][s][kt][lane][0];
                g0[s] = __builtin_amdgcn_mfma_f32_16x16x32_bf16(a0, b1, g0[s], 0, 0, 0);
                g1[s] = __builtin_amdgcn_mfma_f32_16x16x32_bf16(a1, b1, g1[s], 0, 0, 0);
                s16x8 b3 = *(const s16x8*)&Bl[1][s][kt][lane][0];
                u0[s] = __builtin_amdgcn_mfma_f32_16x16x32_bf16(a0, b3, u0[s], 0, 0, 0);
                u1[s] = __builtin_amdgcn_mfma_f32_16x16x32_bf16(a1, b3, u1[s], 0, 0, 0);
            }
        }
        // SwiGLU epilogue; C layout: col = m16 (within 16-slice), row = q*4+r
#pragma unroll
        for (int s = 0; s < 4; ++s) {
#pragma unroll
            for (int r = 0; r < 4; ++r) {
                int rr0 = r0 + q * 4 + r;
                if (rr0 < n_e) {
                    float g = g0[s][r], uu = u0[s][r];
                    float hv = g / (1.f + __expf(-g)) * uu;
                    hbuf[(size_t)el[rr0] * MOE + n0 + s * 16 + m16] = (short)f2bf(hv);
                }
                int rr1 = r0 + 16 + q * 4 + r;
                if (rr1 < n_e) {
                    float g = g1[s][r], uu = u1[s][r];
                    float hv = g / (1.f + __expf(-g)) * uu;
                    hbuf[(size_t)el[rr1] * MOE + n0 + s * 16 + m16] = (short)f2bf(hv);
                }
            }
        }
    }
}

// ---------------- K2: y = H@W2 ----------------------------------------------
// Block = (expert, 128-col group of DIM). Same structure; 64 KB LDS.
__global__ __launch_bounds__(512) void gemm2_k(const short* __restrict__ hbuf,
                                               const float* __restrict__ w2,
                                               const int* __restrict__ counts,
                                               const int* __restrict__ etok,
                                               short* __restrict__ ybuf)
{
    __shared__ short Bl[8][8][64][8];   // s, kt, flane, j = 64 KB

    int e  = blockIdx.x >> 2, cg = blockIdx.x & 3;
    int n0 = cg * 128;
    int tid = threadIdx.x;
    int w = tid >> 6, lane = tid & 63;
    int q = lane >> 4, m16 = lane & 15;

    {
        const float* Wp = w2 + (size_t)e * MOE * DIM + n0;
#pragma unroll 4
        for (int kk = 0; kk < 32; ++kk) {
            int k = w * 32 + kk;
            int kt = k >> 5, qq = (k >> 3) & 3, j = k & 7;
#pragma unroll
            for (int hc = 0; hc < 2; ++hc) {
                int c = hc * 64 + lane;
                Bl[c >> 4][kt][qq * 16 + (c & 15)][j] = (short)f2bf(Wp[(size_t)k * DIM + c]);
            }
        }
    }
    __syncthreads();

    int n_e = min(counts[e], CAP);
    int ntiles = (n_e + 31) >> 5;
    const int* el = etok + e * CAP;

    for (int tile = w; tile < ntiles; tile += 8) {
        int r0 = tile * 32;
        int row0 = r0 + m16, row1 = r0 + 16 + m16;
        int rid0 = el[row0 < n_e ? row0 : n_e - 1];
        int rid1 = el[row1 < n_e ? row1 : n_e - 1];
        const short* A0 = hbuf + (size_t)rid0 * MOE + q * 8;
        const short* A1 = hbuf + (size_t)rid1 * MOE + q * 8;

        f32x4 y0[8], y1[8];
#pragma unroll
        for (int s = 0; s < 8; ++s) { y0[s] = (f32x4)0.f; y1[s] = (f32x4)0.f; }
#pragma unroll
        for (int kt = 0; kt < 8; ++kt) {
            s16x8 a0 = *(const s16x8*)(A0 + kt * 32);
            s16x8 a1 = *(const s16x8*)(A1 + kt * 32);
#pragma unroll
            for (int s = 0; s < 8; ++s) {
                s16x8 b = *(const s16x8*)&Bl[s][kt][lane][0];
                y0[s] = __builtin_amdgcn_mfma_f32_16x16x32_bf16(a0, b, y0[s], 0, 0, 0);
                y1[s] = __builtin_amdgcn_mfma_f32_16x16x32_bf16(a1, b, y1[s], 0, 0, 0);
            }
        }
#pragma unroll
        for (int s = 0; s < 8; ++s) {
#pragma unroll
            for (int r = 0; r < 4; ++r) {
                int rr0 = r0 + q * 4 + r;
                if (rr0 < n_e)
                    ybuf[(size_t)el[rr0] * DIM + n0 + s * 16 + m16] = (short)f2bf(y0[s][r]);
                int rr1 = r0 + 16 + q * 4 + r;
                if (rr1 < n_e)
                    ybuf[(size_t)el[rr1] * DIM + n0 + s * 16 + m16] = (short)f2bf(y1[s][r]);
            }
        }
    }
}

// ---------------- Combine: out[t] = sum_k wt[t,k] * ybuf[t*8+k] ---------------
__global__ __launch_bounds__(256) void combine_k(const short* __restrict__ ybuf,
                                                 const float* __restrict__ wt_of,
                                                 float* __restrict__ out)
{
    int t = blockIdx.x;
    int tid = threadIdx.x;
    const int* yb = (const int*)ybuf;
    float sx = 0.f, sy = 0.f;
#pragma unroll
    for (int k = 0; k < TOPK; ++k) {
        float wk = wt_of[t * TOPK + k];
        int v = yb[(size_t)(t * TOPK + k) * (DIM / 2) + tid];
        float lo = __builtin_bit_cast(float, (unsigned)v << 16);
        float hi = __builtin_bit_cast(float, (unsigned)v & 0xffff0000u);
        sx += wk * lo;
        sy += wk * hi;
    }
    float2 o = {sx, sy};
    ((float2*)out)[(size_t)t * (DIM / 2) + tid] = o;
}

extern "C" void kernel_launch(void* const* d_in, const int* in_sizes, int n_in,
                              void* d_out, int out_size, void* d_ws, size_t ws_size,
                              hipStream_t stream)
{
    const float* x  = (const float*)d_in[0];
    const float* gw = (const float*)d_in[1];
    const float* gb = (const float*)d_in[2];
    const float* w1 = (const float*)d_in[3];
    const float* w3 = (const float*)d_in[4];
    const float* w2 = (const float*)d_in[5];

    char* ws = (char*)d_ws;
    short* xb    = (short*)(ws);                     // 2048*512*2   =  2,097,152
    short* hbuf  = (short*)(ws + 2097152);           // 16384*256*2  =  8,388,608
    short* ybuf  = (short*)(ws + 10485760);          // 16384*512*2  = 16,777,216
    int*   etok  = (int*)  (ws + 27262976);          // 64*1024*4    =    262,144
    float* wt_of = (float*)(ws + 27525120);          // 16384*4      =     65,536
    int*   counts= (int*)  (ws + 27590656);          // 256 B

    hipMemsetAsync(counts, 0, NE * 4, stream);

    gate_fused_k<<<T_TOK / 4, 256, 0, stream>>>(x, gw, gb, counts, etok, wt_of, xb);
    gemm1_k<<<NE * 4, 512, 0, stream>>>(xb, w1, w3, counts, etok, hbuf);
    gemm2_k<<<NE * 4, 512, 0, stream>>>(hbuf, w2, counts, etok, ybuf);
    combine_k<<<T_TOK, 256, 0, stream>>>(ybuf, wt_of, (float*)d_out);
}

// Round 7
// 269.515 us; speedup vs baseline: 1.2896x; 1.2896x over previous
//
#include <hip/hip_runtime.h>

#define T_TOK 2048
#define DIM   512
#define MOE   256
#define NE    64
#define NG    8
#define TOPKG 4
#define TOPK  8
#define CAP   1024
#define MOE_SCALE 2.5f

typedef float f32x4 __attribute__((ext_vector_type(4)));
typedef short s16x8 __attribute__((ext_vector_type(8)));

__device__ __forceinline__ unsigned short f2bf(float f) {
    unsigned u = __builtin_bit_cast(unsigned, f);
    unsigned r = (u + 0x7fffu + ((u >> 16) & 1u)) >> 16;
    return (unsigned short)r;
}

// ---------------- gw transpose: gwT4[k4][e] = float4(gw[e][4k4..4k4+3]) ------
__global__ __launch_bounds__(256) void gwt_k(const float* __restrict__ gw,
                                             float* __restrict__ gwT)
{
    int idx = blockIdx.x * 256 + threadIdx.x;   // e-major, coalesced read
    int e = idx >> 9, k = idx & 511;
    gwT[(size_t)(k >> 2) * 256 + e * 4 + (k & 3)] = gw[idx];
}

// ---------------- Fused gating + x->bf16, one wave per token ------------------
__global__ __launch_bounds__(256) void gate_fused_k(const float* __restrict__ x,
                                                    const float* __restrict__ gwT,
                                                    const float* __restrict__ gb,
                                                    int* __restrict__ counts,
                                                    int* __restrict__ etok,
                                                    float* __restrict__ wt_of,
                                                    short* __restrict__ xb)
{
    __shared__ float xs[4][512];
    int w = threadIdx.x >> 6, lane = threadIdx.x & 63;
    int t = blockIdx.x * 4 + w;

    // stage x row (coalesced) + write bf16 copy
    {
        const float4* xr = (const float4*)(x + (size_t)t * DIM);
        float4 v0 = xr[lane * 2], v1 = xr[lane * 2 + 1];
        *(float4*)&xs[w][lane * 8]     = v0;
        *(float4*)&xs[w][lane * 8 + 4] = v1;
        short o[8];
        o[0] = (short)f2bf(v0.x); o[1] = (short)f2bf(v0.y);
        o[2] = (short)f2bf(v0.z); o[3] = (short)f2bf(v0.w);
        o[4] = (short)f2bf(v1.x); o[5] = (short)f2bf(v1.y);
        o[6] = (short)f2bf(v1.z); o[7] = (short)f2bf(v1.w);
        *(s16x8*)(xb + (size_t)t * DIM + lane * 8) = *(const s16x8*)o;
    }
    __syncthreads();

    // lane e: dot over 512, gwT loads coalesced (lane-consecutive)
    const float4* gt = (const float4*)gwT;
    float a0 = 0.f, a1 = 0.f, a2 = 0.f, a3 = 0.f;
#pragma unroll 4
    for (int k4 = 0; k4 < 128; k4 += 4) {
        float4 g0 = gt[(k4 + 0) * 64 + lane];
        float4 g1 = gt[(k4 + 1) * 64 + lane];
        float4 g2 = gt[(k4 + 2) * 64 + lane];
        float4 g3 = gt[(k4 + 3) * 64 + lane];
        float4 x0 = *(const float4*)&xs[w][(k4 + 0) * 4];
        float4 x1 = *(const float4*)&xs[w][(k4 + 1) * 4];
        float4 x2 = *(const float4*)&xs[w][(k4 + 2) * 4];
        float4 x3 = *(const float4*)&xs[w][(k4 + 3) * 4];
        a0 += g0.x * x0.x + g0.y * x0.y + g0.z * x0.z + g0.w * x0.w;
        a1 += g1.x * x1.x + g1.y * x1.y + g1.z * x1.z + g1.w * x1.w;
        a2 += g2.x * x2.x + g2.y * x2.y + g2.z * x2.z + g2.w * x2.w;
        a3 += g3.x * x3.x + g3.y * x3.y + g3.z * x3.z + g3.w * x3.w;
    }
    float acc = (a0 + a1) + (a2 + a3);
    float sc = 1.f / (1.f + __expf(-acc));   // pre-bias score
    float s  = sc + gb[lane];                 // biased score

    // group top-2 sum within each 8-lane group
    float m1 = s, m2 = -1e30f;
#pragma unroll
    for (int d = 1; d < 8; d <<= 1) {
        float o1 = __shfl_xor(m1, d);
        float o2 = __shfl_xor(m2, d);
        float n1 = fmaxf(m1, o1);
        float n2 = fmaxf(fminf(m1, o1), fmaxf(m2, o2));
        m1 = n1; m2 = n2;
    }
    float gv = m1 + m2;

    // top-4 groups (tie -> lowest group index)
    bool gkeep = false;
#pragma unroll
    for (int it = 0; it < TOPKG; ++it) {
        float m = gv;
#pragma unroll
        for (int d = 1; d < 64; d <<= 1) m = fmaxf(m, __shfl_xor(m, d));
        unsigned long long mask = __ballot(gv == m);
        int ldr = __ffsll(mask) - 1;
        if ((lane >> 3) == (ldr >> 3)) { gkeep = true; gv = -2e30f; }
    }
    float sv = gkeep ? s : -1e30f;

    // top-8 experts (tie -> lowest index)
    float wsum = 0.f;
    int my_e = 0; float my_w = 0.f;
#pragma unroll
    for (int k = 0; k < TOPK; ++k) {
        float m = sv;
#pragma unroll
        for (int d = 1; d < 64; d <<= 1) m = fmaxf(m, __shfl_xor(m, d));
        unsigned long long mask = __ballot(sv == m);
        int l = __ffsll(mask) - 1;
        float wk = __shfl(sc, l);
        wsum += wk;
        if (lane == k) { my_e = l; my_w = wk; }
        if (lane == l) sv = -2e30f;
    }
    float scale = MOE_SCALE / wsum;
    if (lane < TOPK) {
        int p = atomicAdd(&counts[my_e], 1);
        int rid = t * TOPK + lane;           // global slot id
        bool ok = (p < CAP);
        if (ok) etok[my_e * CAP + p] = rid;
        wt_of[rid] = ok ? my_w * scale : 0.f;
    }
}

// ---------------- K1: h = silu(X@W1)*(X@W3) ----------------------------------
// Block = (expert, 32-col group of MOE), 256 thr, 64 KB LDS. W1/W3 slice staged
// once (coalesced fp32 -> bf16 pair-packed dwords, frag-major). 4 waves stream
// 32-row token tiles: per kt = 2 A-loads + 4 ds_read_b128 + 8 MFMA.
__global__ __launch_bounds__(256) void gemm1_k(const short* __restrict__ xb,
                                               const float* __restrict__ w1,
                                               const float* __restrict__ w3,
                                               const int* __restrict__ counts,
                                               const int* __restrict__ etok,
                                               short* __restrict__ hbuf)
{
    __shared__ short Bl[2][2][16][64][8];   // mat, s, kt, flane, j = 64 KB

    int e  = blockIdx.x >> 3, cg = blockIdx.x & 7;
    int n0 = cg * 32;
    int tid = threadIdx.x;
    int w = tid >> 6, lane = tid & 63;
    int q = lane >> 4, m16 = lane & 15;

    // stage: pairs (k, k+1) packed into one dword
#pragma unroll 4
    for (int c = 0; c < 32; ++c) {
        int idx = c * 256 + tid;
        int k2 = idx >> 5, col = idx & 31;
        int k = k2 * 2;
        int kt = k >> 5, qq = (k >> 3) & 3, j = k & 7;
        int s = col >> 4, c15 = col & 15;
        const float* p1 = w1 + ((size_t)e * DIM + k) * MOE + n0 + col;
        const float* p3 = w3 + ((size_t)e * DIM + k) * MOE + n0 + col;
        unsigned d1 = (unsigned)f2bf(p1[0]) | ((unsigned)f2bf(p1[MOE]) << 16);
        unsigned d3 = (unsigned)f2bf(p3[0]) | ((unsigned)f2bf(p3[MOE]) << 16);
        *(unsigned*)&Bl[0][s][kt][qq * 16 + c15][j] = d1;
        *(unsigned*)&Bl[1][s][kt][qq * 16 + c15][j] = d3;
    }
    __syncthreads();

    int n_e = min(counts[e], CAP);
    int ntiles = (n_e + 31) >> 5;
    const int* el = etok + e * CAP;

    for (int tile = w; tile < ntiles; tile += 4) {
        int r0 = tile * 32;
        int row0 = r0 + m16, row1 = r0 + 16 + m16;
        int tok0 = el[row0 < n_e ? row0 : n_e - 1] >> 3;
        int tok1 = el[row1 < n_e ? row1 : n_e - 1] >> 3;
        const short* A0 = xb + (size_t)tok0 * DIM + q * 8;
        const short* A1 = xb + (size_t)tok1 * DIM + q * 8;

        f32x4 g0[2], g1[2], u0[2], u1[2];
#pragma unroll
        for (int s = 0; s < 2; ++s) {
            g0[s] = (f32x4)0.f; g1[s] = (f32x4)0.f;
            u0[s] = (f32x4)0.f; u1[s] = (f32x4)0.f;
        }
#pragma unroll
        for (int kt = 0; kt < 16; ++kt) {
            s16x8 a0 = *(const s16x8*)(A0 + kt * 32);
            s16x8 a1 = *(const s16x8*)(A1 + kt * 32);
#pragma unroll
            for (int s = 0; s < 2; ++s) {
                s16x8 b1 = *(const s16x8*)&Bl[0][s][kt][lane][0];
                g0[s] = __builtin_amdgcn_mfma_f32_16x16x32_bf16(a0, b1, g0[s], 0, 0, 0);
                g1[s] = __builtin_amdgcn_mfma_f32_16x16x32_bf16(a1, b1, g1[s], 0, 0, 0);
                s16x8 b3 = *(const s16x8*)&Bl[1][s][kt][lane][0];
                u0[s] = __builtin_amdgcn_mfma_f32_16x16x32_bf16(a0, b3, u0[s], 0, 0, 0);
                u1[s] = __builtin_amdgcn_mfma_f32_16x16x32_bf16(a1, b3, u1[s], 0, 0, 0);
            }
        }
        // SwiGLU epilogue; C layout: row = q*4+r (+16), col = s*16 + m16
#pragma unroll
        for (int s = 0; s < 2; ++s) {
#pragma unroll
            for (int r = 0; r < 4; ++r) {
                int rr0 = r0 + q * 4 + r;
                if (rr0 < n_e) {
                    float g = g0[s][r], uu = u0[s][r];
                    float hv = g / (1.f + __expf(-g)) * uu;
                    hbuf[(size_t)el[rr0] * MOE + n0 + s * 16 + m16] = (short)f2bf(hv);
                }
                int rr1 = r0 + 16 + q * 4 + r;
                if (rr1 < n_e) {
                    float g = g1[s][r], uu = u1[s][r];
                    float hv = g / (1.f + __expf(-g)) * uu;
                    hbuf[(size_t)el[rr1] * MOE + n0 + s * 16 + m16] = (short)f2bf(hv);
                }
            }
        }
    }
}

// ---------------- K2: y = H@W2 ------------------------------------------------
// Block = (expert, 64-col group of DIM), 256 thr, 32 KB LDS.
__global__ __launch_bounds__(256) void gemm2_k(const short* __restrict__ hbuf,
                                               const float* __restrict__ w2,
                                               const int* __restrict__ counts,
                                               const int* __restrict__ etok,
                                               short* __restrict__ ybuf)
{
    __shared__ short Bl[4][8][64][8];   // s, kt, flane, j = 32 KB

    int e  = blockIdx.x >> 3, cg = blockIdx.x & 7;
    int n0 = cg * 64;
    int tid = threadIdx.x;
    int w = tid >> 6, lane = tid & 63;
    int q = lane >> 4, m16 = lane & 15;

#pragma unroll 4
    for (int c = 0; c < 32; ++c) {
        int idx = c * 256 + tid;
        int k2 = idx >> 6, col = idx & 63;
        int k = k2 * 2;
        int kt = k >> 5, qq = (k >> 3) & 3, j = k & 7;
        int s = col >> 4, c15 = col & 15;
        const float* p2 = w2 + ((size_t)e * MOE + k) * DIM + n0 + col;
        unsigned d2 = (unsigned)f2bf(p2[0]) | ((unsigned)f2bf(p2[DIM]) << 16);
        *(unsigned*)&Bl[s][kt][qq * 16 + c15][j] = d2;
    }
    __syncthreads();

    int n_e = min(counts[e], CAP);
    int ntiles = (n_e + 31) >> 5;
    const int* el = etok + e * CAP;

    for (int tile = w; tile < ntiles; tile += 4) {
        int r0 = tile * 32;
        int row0 = r0 + m16, row1 = r0 + 16 + m16;
        int rid0 = el[row0 < n_e ? row0 : n_e - 1];
        int rid1 = el[row1 < n_e ? row1 : n_e - 1];
        const short* A0 = hbuf + (size_t)rid0 * MOE + q * 8;
        const short* A1 = hbuf + (size_t)rid1 * MOE + q * 8;

        f32x4 y0[4], y1[4];
#pragma unroll
        for (int s = 0; s < 4; ++s) { y0[s] = (f32x4)0.f; y1[s] = (f32x4)0.f; }
#pragma unroll
        for (int kt = 0; kt < 8; ++kt) {
            s16x8 a0 = *(const s16x8*)(A0 + kt * 32);
            s16x8 a1 = *(const s16x8*)(A1 + kt * 32);
#pragma unroll
            for (int s = 0; s < 4; ++s) {
                s16x8 b = *(const s16x8*)&Bl[s][kt][lane][0];
                y0[s] = __builtin_amdgcn_mfma_f32_16x16x32_bf16(a0, b, y0[s], 0, 0, 0);
                y1[s] = __builtin_amdgcn_mfma_f32_16x16x32_bf16(a1, b, y1[s], 0, 0, 0);
            }
        }
#pragma unroll
        for (int s = 0; s < 4; ++s) {
#pragma unroll
            for (int r = 0; r < 4; ++r) {
                int rr0 = r0 + q * 4 + r;
                if (rr0 < n_e)
                    ybuf[(size_t)el[rr0] * DIM + n0 + s * 16 + m16] = (short)f2bf(y0[s][r]);
                int rr1 = r0 + 16 + q * 4 + r;
                if (rr1 < n_e)
                    ybuf[(size_t)el[rr1] * DIM + n0 + s * 16 + m16] = (short)f2bf(y1[s][r]);
            }
        }
    }
}

// ---------------- Combine: out[t] = sum_k wt[t,k] * ybuf[t*8+k] ---------------
__global__ __launch_bounds__(256) void combine_k(const short* __restrict__ ybuf,
                                                 const float* __restrict__ wt_of,
                                                 float* __restrict__ out)
{
    int t = blockIdx.x;
    int tid = threadIdx.x;
    const int* yb = (const int*)ybuf;
    float sx = 0.f, sy = 0.f;
#pragma unroll
    for (int k = 0; k < TOPK; ++k) {
        float wk = wt_of[t * TOPK + k];
        int v = yb[(size_t)(t * TOPK + k) * (DIM / 2) + tid];
        float lo = __builtin_bit_cast(float, (unsigned)v << 16);
        float hi = __builtin_bit_cast(float, (unsigned)v & 0xffff0000u);
        sx += wk * lo;
        sy += wk * hi;
    }
    float2 o = {sx, sy};
    ((float2*)out)[(size_t)t * (DIM / 2) + tid] = o;
}

extern "C" void kernel_launch(void* const* d_in, const int* in_sizes, int n_in,
                              void* d_out, int out_size, void* d_ws, size_t ws_size,
                              hipStream_t stream)
{
    const float* x  = (const float*)d_in[0];
    const float* gw = (const float*)d_in[1];
    const float* gb = (const float*)d_in[2];
    const float* w1 = (const float*)d_in[3];
    const float* w3 = (const float*)d_in[4];
    const float* w2 = (const float*)d_in[5];

    char* ws = (char*)d_ws;
    short* xb    = (short*)(ws);                     // 2048*512*2   =  2,097,152
    short* hbuf  = (short*)(ws + 2097152);           // 16384*256*2  =  8,388,608
    short* ybuf  = (short*)(ws + 10485760);          // 16384*512*2  = 16,777,216
    float* gwT   = (float*)(ws + 27262976);          // 512*64*4     =    131,072
    int*   etok  = (int*)  (ws + 27394048);          // 64*1024*4    =    262,144
    float* wt_of = (float*)(ws + 27656192);          // 16384*4      =     65,536
    int*   counts= (int*)  (ws + 27721728);          // 256 B

    hipMemsetAsync(counts, 0, NE * 4, stream);

    gwt_k<<<128, 256, 0, stream>>>(gw, gwT);
    gate_fused_k<<<T_TOK / 4, 256, 0, stream>>>(x, gwT, gb, counts, etok, wt_of, xb);
    gemm1_k<<<NE * 8, 256, 0, stream>>>(xb, w1, w3, counts, etok, hbuf);
    gemm2_k<<<NE * 8, 256, 0, stream>>>(hbuf, w2, counts, etok, ybuf);
    combine_k<<<T_TOK, 256, 0, stream>>>(ybuf, wt_of, (float*)d_out);
}

// Round 8
// 265.965 us; speedup vs baseline: 1.3068x; 1.0133x over previous
//
#include <hip/hip_runtime.h>

#define T_TOK 2048
#define DIM   512
#define MOE   256
#define NE    64
#define NG    8
#define TOPKG 4
#define TOPK  8
#define CAP   1024
#define MOE_SCALE 2.5f

typedef float f32x4 __attribute__((ext_vector_type(4)));
typedef short s16x8 __attribute__((ext_vector_type(8)));

__device__ __forceinline__ unsigned short f2bf(float f) {
    unsigned u = __builtin_bit_cast(unsigned, f);
    unsigned r = (u + 0x7fffu + ((u >> 16) & 1u)) >> 16;
    return (unsigned short)r;
}
__device__ __forceinline__ unsigned pk2(float lo, float hi) {
    return (unsigned)f2bf(lo) | ((unsigned)f2bf(hi) << 16);
}

// ---------------- gw transpose: gwT4[k4][e] = float4(gw[e][4k4..4k4+3]) ------
__global__ __launch_bounds__(256) void gwt_k(const float* __restrict__ gw,
                                             float* __restrict__ gwT)
{
    int idx = blockIdx.x * 256 + threadIdx.x;   // e-major, coalesced read
    int e = idx >> 9, k = idx & 511;
    gwT[(size_t)(k >> 2) * 256 + e * 4 + (k & 3)] = gw[idx];
}

// ---------------- Fused gating + x->bf16, one wave per token ------------------
__global__ __launch_bounds__(256) void gate_fused_k(const float* __restrict__ x,
                                                    const float* __restrict__ gwT,
                                                    const float* __restrict__ gb,
                                                    int* __restrict__ counts,
                                                    int* __restrict__ etok,
                                                    float* __restrict__ wt_of,
                                                    short* __restrict__ xb)
{
    __shared__ float xs[4][512];
    int w = threadIdx.x >> 6, lane = threadIdx.x & 63;
    int t = blockIdx.x * 4 + w;

    // stage x row (coalesced) + write bf16 copy
    {
        const float4* xr = (const float4*)(x + (size_t)t * DIM);
        float4 v0 = xr[lane * 2], v1 = xr[lane * 2 + 1];
        *(float4*)&xs[w][lane * 8]     = v0;
        *(float4*)&xs[w][lane * 8 + 4] = v1;
        short o[8];
        o[0] = (short)f2bf(v0.x); o[1] = (short)f2bf(v0.y);
        o[2] = (short)f2bf(v0.z); o[3] = (short)f2bf(v0.w);
        o[4] = (short)f2bf(v1.x); o[5] = (short)f2bf(v1.y);
        o[6] = (short)f2bf(v1.z); o[7] = (short)f2bf(v1.w);
        *(s16x8*)(xb + (size_t)t * DIM + lane * 8) = *(const s16x8*)o;
    }
    __syncthreads();

    // lane e: dot over 512, gwT loads coalesced (lane-consecutive)
    const float4* gt = (const float4*)gwT;
    float a0 = 0.f, a1 = 0.f, a2 = 0.f, a3 = 0.f;
#pragma unroll 4
    for (int k4 = 0; k4 < 128; k4 += 4) {
        float4 g0 = gt[(k4 + 0) * 64 + lane];
        float4 g1 = gt[(k4 + 1) * 64 + lane];
        float4 g2 = gt[(k4 + 2) * 64 + lane];
        float4 g3 = gt[(k4 + 3) * 64 + lane];
        float4 x0 = *(const float4*)&xs[w][(k4 + 0) * 4];
        float4 x1 = *(const float4*)&xs[w][(k4 + 1) * 4];
        float4 x2 = *(const float4*)&xs[w][(k4 + 2) * 4];
        float4 x3 = *(const float4*)&xs[w][(k4 + 3) * 4];
        a0 += g0.x * x0.x + g0.y * x0.y + g0.z * x0.z + g0.w * x0.w;
        a1 += g1.x * x1.x + g1.y * x1.y + g1.z * x1.z + g1.w * x1.w;
        a2 += g2.x * x2.x + g2.y * x2.y + g2.z * x2.z + g2.w * x2.w;
        a3 += g3.x * x3.x + g3.y * x3.y + g3.z * x3.z + g3.w * x3.w;
    }
    float acc = (a0 + a1) + (a2 + a3);
    float sc = 1.f / (1.f + __expf(-acc));   // pre-bias score
    float s  = sc + gb[lane];                 // biased score

    // group top-2 sum within each 8-lane group
    float m1 = s, m2 = -1e30f;
#pragma unroll
    for (int d = 1; d < 8; d <<= 1) {
        float o1 = __shfl_xor(m1, d);
        float o2 = __shfl_xor(m2, d);
        float n1 = fmaxf(m1, o1);
        float n2 = fmaxf(fminf(m1, o1), fmaxf(m2, o2));
        m1 = n1; m2 = n2;
    }
    float gv = m1 + m2;

    // top-4 groups (tie -> lowest group index)
    bool gkeep = false;
#pragma unroll
    for (int it = 0; it < TOPKG; ++it) {
        float m = gv;
#pragma unroll
        for (int d = 1; d < 64; d <<= 1) m = fmaxf(m, __shfl_xor(m, d));
        unsigned long long mask = __ballot(gv == m);
        int ldr = __ffsll(mask) - 1;
        if ((lane >> 3) == (ldr >> 3)) { gkeep = true; gv = -2e30f; }
    }
    float sv = gkeep ? s : -1e30f;

    // top-8 experts (tie -> lowest index)
    float wsum = 0.f;
    int my_e = 0; float my_w = 0.f;
#pragma unroll
    for (int k = 0; k < TOPK; ++k) {
        float m = sv;
#pragma unroll
        for (int d = 1; d < 64; d <<= 1) m = fmaxf(m, __shfl_xor(m, d));
        unsigned long long mask = __ballot(sv == m);
        int l = __ffsll(mask) - 1;
        float wk = __shfl(sc, l);
        wsum += wk;
        if (lane == k) { my_e = l; my_w = wk; }
        if (lane == l) sv = -2e30f;
    }
    float scale = MOE_SCALE / wsum;
    if (lane < TOPK) {
        int p = atomicAdd(&counts[my_e], 1);
        int rid = t * TOPK + lane;           // global slot id
        bool ok = (p < CAP);
        if (ok) etok[my_e * CAP + p] = rid;
        wt_of[rid] = ok ? my_w * scale : 0.f;
    }
}

// ---------------- K1: h = silu(X@W1)*(X@W3) ----------------------------------
// Block = (expert, 32-col group of MOE), 256 thr, 64 KB LDS. Staging now uses
// float4 loads (row-pair per thread, 1 KB/wave-instr) + dword-packed LDS
// writes — 32 independent 16B loads/thread for deep MLP.
__global__ __launch_bounds__(256) void gemm1_k(const short* __restrict__ xb,
                                               const float* __restrict__ w1,
                                               const float* __restrict__ w3,
                                               const int* __restrict__ counts,
                                               const int* __restrict__ etok,
                                               short* __restrict__ hbuf)
{
    __shared__ short Bl[2][2][16][64][8];   // mat, s, kt, flane, j = 64 KB

    int e  = blockIdx.x >> 3, cg = blockIdx.x & 7;
    int n0 = cg * 32;
    int tid = threadIdx.x;
    int w = tid >> 6, lane = tid & 63;
    int q = lane >> 4, m16 = lane & 15;

    // ---- stage: 2048 (row-pair, col-quad) items, 8 per thread ----
    const float* W1e = w1 + (size_t)e * DIM * MOE + n0;
    const float* W3e = w3 + (size_t)e * DIM * MOE + n0;
#pragma unroll
    for (int it = 0; it < 8; ++it) {
        int idx = it * 256 + tid;        // 0..2047
        int r2  = idx >> 3;              // row pair 0..255
        int cq  = (idx & 7) * 4;         // col 0,4,..,28 (quad stays in one s)
        int k   = r2 * 2;
        int kt = k >> 5, qq = (k >> 3) & 3, j0 = k & 7;
        int s = cq >> 4, c15 = cq & 15;
        const float* p1 = W1e + (size_t)k * MOE + cq;
        const float* p3 = W3e + (size_t)k * MOE + cq;
        float4 lo1 = *(const float4*)p1;
        float4 hi1 = *(const float4*)(p1 + MOE);
        float4 lo3 = *(const float4*)p3;
        float4 hi3 = *(const float4*)(p3 + MOE);
        unsigned* b0 = (unsigned*)&Bl[0][s][kt][qq * 16 + c15][j0];
        b0[0]  = pk2(lo1.x, hi1.x);
        b0[4]  = pk2(lo1.y, hi1.y);
        b0[8]  = pk2(lo1.z, hi1.z);
        b0[12] = pk2(lo1.w, hi1.w);
        unsigned* b1 = (unsigned*)&Bl[1][s][kt][qq * 16 + c15][j0];
        b1[0]  = pk2(lo3.x, hi3.x);
        b1[4]  = pk2(lo3.y, hi3.y);
        b1[8]  = pk2(lo3.z, hi3.z);
        b1[12] = pk2(lo3.w, hi3.w);
    }
    __syncthreads();

    int n_e = min(counts[e], CAP);
    int ntiles = (n_e + 31) >> 5;
    const int* el = etok + e * CAP;

    for (int tile = w; tile < ntiles; tile += 4) {
        int r0 = tile * 32;
        int row0 = r0 + m16, row1 = r0 + 16 + m16;
        int tok0 = el[row0 < n_e ? row0 : n_e - 1] >> 3;
        int tok1 = el[row1 < n_e ? row1 : n_e - 1] >> 3;
        const short* A0 = xb + (size_t)tok0 * DIM + q * 8;
        const short* A1 = xb + (size_t)tok1 * DIM + q * 8;

        f32x4 g0[2], g1[2], u0[2], u1[2];
#pragma unroll
        for (int s = 0; s < 2; ++s) {
            g0[s] = (f32x4)0.f; g1[s] = (f32x4)0.f;
            u0[s] = (f32x4)0.f; u1[s] = (f32x4)0.f;
        }
#pragma unroll
        for (int kt = 0; kt < 16; ++kt) {
            s16x8 a0 = *(const s16x8*)(A0 + kt * 32);
            s16x8 a1 = *(const s16x8*)(A1 + kt * 32);
#pragma unroll
            for (int s = 0; s < 2; ++s) {
                s16x8 b1 = *(const s16x8*)&Bl[0][s][kt][lane][0];
                g0[s] = __builtin_amdgcn_mfma_f32_16x16x32_bf16(a0, b1, g0[s], 0, 0, 0);
                g1[s] = __builtin_amdgcn_mfma_f32_16x16x32_bf16(a1, b1, g1[s], 0, 0, 0);
                s16x8 b3 = *(const s16x8*)&Bl[1][s][kt][lane][0];
                u0[s] = __builtin_amdgcn_mfma_f32_16x16x32_bf16(a0, b3, u0[s], 0, 0, 0);
                u1[s] = __builtin_amdgcn_mfma_f32_16x16x32_bf16(a1, b3, u1[s], 0, 0, 0);
            }
        }
        // SwiGLU epilogue; C layout: row = q*4+r (+16), col = s*16 + m16
#pragma unroll
        for (int s = 0; s < 2; ++s) {
#pragma unroll
            for (int r = 0; r < 4; ++r) {
                int rr0 = r0 + q * 4 + r;
                if (rr0 < n_e) {
                    float g = g0[s][r], uu = u0[s][r];
                    float hv = g / (1.f + __expf(-g)) * uu;
                    hbuf[(size_t)el[rr0] * MOE + n0 + s * 16 + m16] = (short)f2bf(hv);
                }
                int rr1 = r0 + 16 + q * 4 + r;
                if (rr1 < n_e) {
                    float g = g1[s][r], uu = u1[s][r];
                    float hv = g / (1.f + __expf(-g)) * uu;
                    hbuf[(size_t)el[rr1] * MOE + n0 + s * 16 + m16] = (short)f2bf(hv);
                }
            }
        }
    }
}

// ---------------- K2: y = H@W2 ------------------------------------------------
// Block = (expert, 64-col group of DIM), 256 thr, 32 KB LDS, float4 staging.
__global__ __launch_bounds__(256) void gemm2_k(const short* __restrict__ hbuf,
                                               const float* __restrict__ w2,
                                               const int* __restrict__ counts,
                                               const int* __restrict__ etok,
                                               short* __restrict__ ybuf)
{
    __shared__ short Bl[4][8][64][8];   // s, kt, flane, j = 32 KB

    int e  = blockIdx.x >> 3, cg = blockIdx.x & 7;
    int n0 = cg * 64;
    int tid = threadIdx.x;
    int w = tid >> 6, lane = tid & 63;
    int q = lane >> 4, m16 = lane & 15;

    const float* W2e = w2 + (size_t)e * MOE * DIM + n0;
#pragma unroll
    for (int it = 0; it < 8; ++it) {
        int idx = it * 256 + tid;        // 0..2047
        int r2  = idx >> 4;              // row pair 0..127
        int cq  = (idx & 15) * 4;        // col 0,4,..,60
        int k   = r2 * 2;
        int kt = k >> 5, qq = (k >> 3) & 3, j0 = k & 7;
        int s = cq >> 4, c15 = cq & 15;
        const float* p2 = W2e + (size_t)k * DIM + cq;
        float4 lo = *(const float4*)p2;
        float4 hi = *(const float4*)(p2 + DIM);
        unsigned* b = (unsigned*)&Bl[s][kt][qq * 16 + c15][j0];
        b[0]  = pk2(lo.x, hi.x);
        b[4]  = pk2(lo.y, hi.y);
        b[8]  = pk2(lo.z, hi.z);
        b[12] = pk2(lo.w, hi.w);
    }
    __syncthreads();

    int n_e = min(counts[e], CAP);
    int ntiles = (n_e + 31) >> 5;
    const int* el = etok + e * CAP;

    for (int tile = w; tile < ntiles; tile += 4) {
        int r0 = tile * 32;
        int row0 = r0 + m16, row1 = r0 + 16 + m16;
        int rid0 = el[row0 < n_e ? row0 : n_e - 1];
        int rid1 = el[row1 < n_e ? row1 : n_e - 1];
        const short* A0 = hbuf + (size_t)rid0 * MOE + q * 8;
        const short* A1 = hbuf + (size_t)rid1 * MOE + q * 8;

        f32x4 y0[4], y1[4];
#pragma unroll
        for (int s = 0; s < 4; ++s) { y0[s] = (f32x4)0.f; y1[s] = (f32x4)0.f; }
#pragma unroll
        for (int kt = 0; kt < 8; ++kt) {
            s16x8 a0 = *(const s16x8*)(A0 + kt * 32);
            s16x8 a1 = *(const s16x8*)(A1 + kt * 32);
#pragma unroll
            for (int s = 0; s < 4; ++s) {
                s16x8 b = *(const s16x8*)&Bl[s][kt][lane][0];
                y0[s] = __builtin_amdgcn_mfma_f32_16x16x32_bf16(a0, b, y0[s], 0, 0, 0);
                y1[s] = __builtin_amdgcn_mfma_f32_16x16x32_bf16(a1, b, y1[s], 0, 0, 0);
            }
        }
#pragma unroll
        for (int s = 0; s < 4; ++s) {
#pragma unroll
            for (int r = 0; r < 4; ++r) {
                int rr0 = r0 + q * 4 + r;
                if (rr0 < n_e)
                    ybuf[(size_t)el[rr0] * DIM + n0 + s * 16 + m16] = (short)f2bf(y0[s][r]);
                int rr1 = r0 + 16 + q * 4 + r;
                if (rr1 < n_e)
                    ybuf[(size_t)el[rr1] * DIM + n0 + s * 16 + m16] = (short)f2bf(y1[s][r]);
            }
        }
    }
}

// ---------------- Combine: out[t] = sum_k wt[t,k] * ybuf[t*8+k] ---------------
__global__ __launch_bounds__(256) void combine_k(const short* __restrict__ ybuf,
                                                 const float* __restrict__ wt_of,
                                                 float* __restrict__ out)
{
    int t = blockIdx.x;
    int tid = threadIdx.x;
    const int* yb = (const int*)ybuf;
    float sx = 0.f, sy = 0.f;
#pragma unroll
    for (int k = 0; k < TOPK; ++k) {
        float wk = wt_of[t * TOPK + k];
        int v = yb[(size_t)(t * TOPK + k) * (DIM / 2) + tid];
        float lo = __builtin_bit_cast(float, (unsigned)v << 16);
        float hi = __builtin_bit_cast(float, (unsigned)v & 0xffff0000u);
        sx += wk * lo;
        sy += wk * hi;
    }
    float2 o = {sx, sy};
    ((float2*)out)[(size_t)t * (DIM / 2) + tid] = o;
}

extern "C" void kernel_launch(void* const* d_in, const int* in_sizes, int n_in,
                              void* d_out, int out_size, void* d_ws, size_t ws_size,
                              hipStream_t stream)
{
    const float* x  = (const float*)d_in[0];
    const float* gw = (const float*)d_in[1];
    const float* gb = (const float*)d_in[2];
    const float* w1 = (const float*)d_in[3];
    const float* w3 = (const float*)d_in[4];
    const float* w2 = (const float*)d_in[5];

    char* ws = (char*)d_ws;
    short* xb    = (short*)(ws);                     // 2048*512*2   =  2,097,152
    short* hbuf  = (short*)(ws + 2097152);           // 16384*256*2  =  8,388,608
    short* ybuf  = (short*)(ws + 10485760);          // 16384*512*2  = 16,777,216
    float* gwT   = (float*)(ws + 27262976);          // 512*64*4     =    131,072
    int*   etok  = (int*)  (ws + 27394048);          // 64*1024*4    =    262,144
    float* wt_of = (float*)(ws + 27656192);          // 16384*4      =     65,536
    int*   counts= (int*)  (ws + 27721728);          // 256 B

    hipMemsetAsync(counts, 0, NE * 4, stream);

    gwt_k<<<128, 256, 0, stream>>>(gw, gwT);
    gate_fused_k<<<T_TOK / 4, 256, 0, stream>>>(x, gwT, gb, counts, etok, wt_of, xb);
    gemm1_k<<<NE * 8, 256, 0, stream>>>(xb, w1, w3, counts, etok, hbuf);
    gemm2_k<<<NE * 8, 256, 0, stream>>>(hbuf, w2, counts, etok, ybuf);
    combine_k<<<T_TOK, 256, 0, stream>>>(ybuf, wt_of, (float*)d_out);
}